// Round 7
// baseline (377.593 us; speedup 1.0000x reference)
//
#include <hip/hip_runtime.h>
#include <hip/hip_bf16.h>
#include <stdint.h>

// TemporalAttention for MI355X (gfx950). B=16, N=256, T=128, H=128.
// R7: reuse tiling to cut LDS reads/MFMA.
//     Projections: 8 waves = 4 row-groups x 2 col-groups (32 rows x 64 cols each),
//       G1 A-frags from prefetched regs; Q held in regs, written after barrier.
//     Attention: 4 waves x 32 s-cols (R5-proven code), waves 4-7 barrier+V^T only.
//     Same double-buffered XOR-swizzled 2x32KB weight LDS as R5/R6.

typedef __bf16 bf16;
typedef __bf16 bf16x4 __attribute__((ext_vector_type(4)));
typedef __bf16 bf16x8 __attribute__((ext_vector_type(8)));
typedef float  f32x4  __attribute__((ext_vector_type(4)));

#define MFMA16(a, b, c) __builtin_amdgcn_mfma_f32_16x16x32_bf16((a), (b), (c), 0, 0, 0)

__device__ __forceinline__ int allBytesNonzero(unsigned v) {
    return ((v - 0x01010101u) & ~v & 0x80808080u) == 0u;
}

__device__ __forceinline__ bf16x8 cvt8(const float* p) {
    float4 f0 = *reinterpret_cast<const float4*>(p);
    float4 f1 = *reinterpret_cast<const float4*>(p + 4);
    bf16x8 r;
    r[0] = (bf16)f0.x; r[1] = (bf16)f0.y; r[2] = (bf16)f0.z; r[3] = (bf16)f0.w;
    r[4] = (bf16)f1.x; r[5] = (bf16)f1.y; r[6] = (bf16)f1.z; r[7] = (bf16)f1.w;
    return r;
}

// branchless erf-GELU, A&S 7.1.26 (|err| < 1.5e-7)
__device__ __forceinline__ float gelu_erf(float v) {
    float x  = v * 0.70710678118654752f;
    float ax = fabsf(x);
    float t  = __builtin_amdgcn_rcpf(1.0f + 0.3275911f * ax);
    float p  = ((((1.061405429f * t - 1.453152027f) * t + 1.421413741f) * t
                 - 0.284496736f) * t + 0.254829592f) * t;
    float er = 1.0f - p * __expf(-ax * ax);
    er = copysignf(er, x);
    return 0.5f * v * (1.0f + er);
}

// Swizzled weight-fragment read from a 32KB LDS weight slot.
// Logical (row, k0..k0+7) lives at elem row*128 + (k0 ^ ((row&15)<<3)).
__device__ __forceinline__ bf16x8 ldw(const bf16* w, int row, int k0) {
    return *reinterpret_cast<const bf16x8*>(w + row * 128 + (k0 ^ ((row & 15) << 3)));
}

// ---- pre-kernel 1: transpose W1(=W_in[0:128]), Wq, Wk, Wv, Wo to bf16 [h][k] ----
__global__ void prep_weights(const float* __restrict__ W_in,
                             const float* __restrict__ Wq, const float* __restrict__ Wk,
                             const float* __restrict__ Wv, const float* __restrict__ Wo,
                             bf16* __restrict__ dst)
{
    int idx = blockIdx.x * 256 + threadIdx.x;
    if (idx >= 5 * 16384) return;
    int m = idx >> 14, r = idx & 16383;
    int h = r >> 7, k = r & 127;
    const float* src = (m == 0) ? W_in : (m == 1) ? Wq : (m == 2) ? Wk : (m == 3) ? Wv : Wo;
    dst[(m << 14) + h * 128 + k] = (bf16)src[k * 128 + h];  // dst[m][h][k] = W[k][h]
}

// ---- pre-kernel 2: npart[n][h] = E_node[nf[n]] @ W_in[256:384] (f32) ----
__global__ void prep_npart(const int* __restrict__ nf, const float* __restrict__ E_node,
                           const float* __restrict__ W_in, float* __restrict__ npart)
{
    int n = blockIdx.x, h = threadIdx.x;
    int node = nf[n];
    const float* e = E_node + node * 128;
    float acc = 0.f;
    for (int k = 0; k < 128; ++k) acc += e[k] * W_in[(256 + k) * 128 + h];
    npart[n * 128 + h] = acc;
}

// ---- pre-kernel 3: biasT[b][h][t] (t fastest for float4 epilogue loads) ----
__global__ void prep_bias(const float* __restrict__ ex, const float* __restrict__ W_t,
                          const float* __restrict__ b_t, const float* __restrict__ W_in,
                          const float* __restrict__ b_in, float* __restrict__ biasT)
{
    const int bt = blockIdx.x;          // b*128 + t
    const int b = bt >> 7;
    const int t = bt & 127;
    const int h = threadIdx.x;
    __shared__ float te[128];
    float v = b_t[h];
    const float* exr = ex + (size_t)bt * 32;
    for (int d = 0; d < 32; ++d) v += exr[d] * W_t[d * 128 + h];
    te[h] = v;
    __syncthreads();
    float acc = b_in[h];
    const float ninv = -9.210340371976184f / 128.0f;   // -ln(10000)/H
    for (int j = 0; j < 64; ++j) {
        float div = expf((float)(2 * j) * ninv);
        float ang = (float)t * div;
        acc += sinf(ang) * W_in[(2 * j) * 128 + h] + cosf(ang) * W_in[(2 * j + 1) * 128 + h];
    }
    for (int k = 0; k < 128; ++k) acc += te[k] * W_in[(128 + k) * 128 + h];
    biasT[(size_t)b * 16384 + h * 128 + t] = acc;
}

// ---- main fused kernel: 1 block per (b,n), 8 waves ----
// Projections: wave (wr=w&3, wc=w>>2) owns rows [32wr,32wr+32) x cols [64wc,64wc+64).
// Attention: waves 0-3 own s in [32w, 32w+32); waves 4-7 barriers + V^T write only.
// MFMA 16x16x32: A row=lane&15,k=(lane>>4)*8+j; B col=lane&15; C/D col=lane&15,row=(lane>>4)*4+reg.
#define STAGE_ISSUE(SRC)                                                        \
    {                                                                           \
        _Pragma("unroll")                                                       \
        for (int i = 0; i < 4; ++i)                                             \
            stg[i] = *reinterpret_cast<const bf16x8*>((SRC) + (tid + i * 512) * 8); \
    }
#define STAGE_WRITE(BUF)                                                        \
    {                                                                           \
        _Pragma("unroll")                                                       \
        for (int i = 0; i < 4; ++i) {                                           \
            int m_ = tid + i * 512;                                             \
            int row_ = m_ >> 4, slot_ = m_ & 15;                                \
            *reinterpret_cast<bf16x8*>(&sW[BUF][row_ * 128 + 8 * (slot_ ^ (row_ & 15))]) = stg[i]; \
        }                                                                       \
    }

__global__ __launch_bounds__(512, 2) void fused_main(
    const float* __restrict__ xf, const unsigned char* __restrict__ mask,
    const bf16* __restrict__ wsW, const float* __restrict__ biasT,
    const float* __restrict__ npart,
    const float* __restrict__ bq, const float* __restrict__ bk,
    const float* __restrict__ bv, const float* __restrict__ bo,
    float* __restrict__ out)
{
    const bf16* W1T = wsW;
    const bf16* WqT = wsW + 16384;
    const bf16* WkT = wsW + 32768;
    const bf16* WvT = wsW + 49152;
    const bf16* WoT = wsW + 65536;

    __shared__ bf16 sX[128][136];    // X -> Q -> P -> rec
    __shared__ bf16 sKV[128][136];   // K[t][h] -> V^T[h][t]
    __shared__ bf16 sW[2][16384];    // double-buffered weight slots (XOR-swizzled)
    __shared__ float sTm[128];

    const int bn = blockIdx.x;
    const int b  = bn >> 8;
    const int n  = bn & 255;
    const int tid  = (int)threadIdx.x;
    const int w    = tid >> 6;      // 0..7
    const int lane = tid & 63;
    const int c = lane & 15;
    const int g = lane >> 4;
    const int wr = w & 3;           // projection row-group
    const int wc = w >> 2;          // projection col-group
    const int r0 = wr << 5;         // row base (t), 32 rows
    const int h0 = wc << 6;         // col base (h), 64 cols

    const f32x4 FZ = {0.f, 0.f, 0.f, 0.f};
    bf16x8 stg[4];

    // ---- t_mask[t] = all(mask[b,n,t,:]) ----
    if (tid < 128) {
        const uint4* mp = reinterpret_cast<const uint4*>(mask + ((size_t)bn * 128 + tid) * 128);
        int ok = 1;
        #pragma unroll
        for (int i = 0; i < 8; ++i) {
            uint4 u = mp[i];
            ok &= allBytesNonzero(u.x) & allBytesNonzero(u.y)
                & allBytesNonzero(u.z) & allBytesNonzero(u.w);
        }
        sTm[tid] = ok ? 1.0f : 0.0f;
    }

    // ---- stage W1 -> sW[0]; prefetch this wave's xf A-fragments (2 row-tiles) ----
    STAGE_ISSUE(W1T);
    bf16x8 af[2][4];
    {
        const float* xfb = xf + (size_t)bn * 16384;
        #pragma unroll
        for (int rt = 0; rt < 2; ++rt)
            #pragma unroll
            for (int kk = 0; kk < 4; ++kk)
                af[rt][kk] = cvt8(xfb + (r0 + rt * 16 + c) * 128 + kk * 32 + g * 8);
    }
    STAGE_WRITE(0);
    __syncthreads();                      // #1: sW[0]=W1

    // ---------- G1: X = gelu(xf@W1 + biasT + npart) -> sX [32 rows x 64 cols] ----------
    STAGE_ISSUE(WkT);
    {
        f32x4 acc[2][4];
        #pragma unroll
        for (int rt = 0; rt < 2; ++rt)
            #pragma unroll
            for (int ct = 0; ct < 4; ++ct) acc[rt][ct] = FZ;
        #pragma unroll
        for (int kk = 0; kk < 4; ++kk) {
            const int k0 = kk * 32 + g * 8;
            #pragma unroll
            for (int ct = 0; ct < 4; ++ct) {
                bf16x8 bw = ldw(&sW[0][0], h0 + ct * 16 + c, k0);
                acc[0][ct] = MFMA16(af[0][kk], bw, acc[0][ct]);
                acc[1][ct] = MFMA16(af[1][kk], bw, acc[1][ct]);
            }
        }
        const float* biasB = biasT + (size_t)b * 16384;
        const float* npRow = npart + n * 128;
        #pragma unroll
        for (int ct = 0; ct < 4; ++ct) {
            const int h = h0 + ct * 16 + c;
            const float npv = npRow[h];
            #pragma unroll
            for (int rt = 0; rt < 2; ++rt) {
                const int t0 = r0 + rt * 16 + g * 4;
                const float4 bb = *reinterpret_cast<const float4*>(biasB + h * 128 + t0);
                const float bbr[4] = {bb.x, bb.y, bb.z, bb.w};
                #pragma unroll
                for (int r = 0; r < 4; ++r)
                    sX[t0 + r][h] = (bf16)gelu_erf(acc[rt][ct][r] + bbr[r] + npv);
            }
        }
    }
    STAGE_WRITE(1);
    __syncthreads();                      // #2: sW[1]=Wk, sX=X

    // ---------- K = X@Wk + bk -> sKV ----------
    STAGE_ISSUE(WvT);
    {
        f32x4 acc[2][4];
        #pragma unroll
        for (int rt = 0; rt < 2; ++rt)
            #pragma unroll
            for (int ct = 0; ct < 4; ++ct) acc[rt][ct] = FZ;
        #pragma unroll
        for (int kk = 0; kk < 4; ++kk) {
            const int k0 = kk * 32 + g * 8;
            bf16x8 a0 = *reinterpret_cast<const bf16x8*>(&sX[r0 + c][k0]);
            bf16x8 a1 = *reinterpret_cast<const bf16x8*>(&sX[r0 + 16 + c][k0]);
            #pragma unroll
            for (int ct = 0; ct < 4; ++ct) {
                bf16x8 bw = ldw(&sW[1][0], h0 + ct * 16 + c, k0);
                acc[0][ct] = MFMA16(a0, bw, acc[0][ct]);
                acc[1][ct] = MFMA16(a1, bw, acc[1][ct]);
            }
        }
        #pragma unroll
        for (int ct = 0; ct < 4; ++ct) {
            const int h = h0 + ct * 16 + c;
            const float bkv = bk[h];
            #pragma unroll
            for (int rt = 0; rt < 2; ++rt)
                #pragma unroll
                for (int r = 0; r < 4; ++r)
                    sKV[r0 + rt * 16 + g * 4 + r][h] = (bf16)(acc[rt][ct][r] + bkv);
        }
    }
    STAGE_WRITE(0);                       // Wv -> sW[0]
    __syncthreads();                      // #3

    // ---------- V = X@Wv + bv -> vpk regs ----------
    bf16x4 vpk[2][4];
    STAGE_ISSUE(WqT);
    {
        f32x4 acc[2][4];
        #pragma unroll
        for (int rt = 0; rt < 2; ++rt)
            #pragma unroll
            for (int ct = 0; ct < 4; ++ct) acc[rt][ct] = FZ;
        #pragma unroll
        for (int kk = 0; kk < 4; ++kk) {
            const int k0 = kk * 32 + g * 8;
            bf16x8 a0 = *reinterpret_cast<const bf16x8*>(&sX[r0 + c][k0]);
            bf16x8 a1 = *reinterpret_cast<const bf16x8*>(&sX[r0 + 16 + c][k0]);
            #pragma unroll
            for (int ct = 0; ct < 4; ++ct) {
                bf16x8 bw = ldw(&sW[0][0], h0 + ct * 16 + c, k0);
                acc[0][ct] = MFMA16(a0, bw, acc[0][ct]);
                acc[1][ct] = MFMA16(a1, bw, acc[1][ct]);
            }
        }
        #pragma unroll
        for (int ct = 0; ct < 4; ++ct) {
            const float bvv = bv[h0 + ct * 16 + c];
            #pragma unroll
            for (int rt = 0; rt < 2; ++rt)
                #pragma unroll
                for (int r = 0; r < 4; ++r)
                    vpk[rt][ct][r] = (bf16)(acc[rt][ct][r] + bvv);
        }
    }
    STAGE_WRITE(1);                       // Wq -> sW[1]
    __syncthreads();                      // #4

    // ---------- Q = X@Wq + bq -> regs (write deferred: col-split reads cross rows) ----------
    f32x4 aq[2][4];
    STAGE_ISSUE(WoT);
    {
        #pragma unroll
        for (int rt = 0; rt < 2; ++rt)
            #pragma unroll
            for (int ct = 0; ct < 4; ++ct) aq[rt][ct] = FZ;
        #pragma unroll
        for (int kk = 0; kk < 4; ++kk) {
            const int k0 = kk * 32 + g * 8;
            bf16x8 a0 = *reinterpret_cast<const bf16x8*>(&sX[r0 + c][k0]);
            bf16x8 a1 = *reinterpret_cast<const bf16x8*>(&sX[r0 + 16 + c][k0]);
            #pragma unroll
            for (int ct = 0; ct < 4; ++ct) {
                bf16x8 bw = ldw(&sW[1][0], h0 + ct * 16 + c, k0);
                aq[0][ct] = MFMA16(a0, bw, aq[0][ct]);
                aq[1][ct] = MFMA16(a1, bw, aq[1][ct]);
            }
        }
    }
    STAGE_WRITE(0);                       // Wo -> sW[0]
    __syncthreads();                      // #5a: all X reads done

    {
        #pragma unroll
        for (int ct = 0; ct < 4; ++ct) {
            const int h = h0 + ct * 16 + c;
            const float bqv = bq[h];
            #pragma unroll
            for (int rt = 0; rt < 2; ++rt)
                #pragma unroll
                for (int r = 0; r < 4; ++r)
                    sX[r0 + rt * 16 + g * 4 + r][h] = (bf16)(aq[rt][ct][r] + bqv);
        }
    }
    __syncthreads();                      // #5b: Q published

    const float rs = 0.08838834764831845f;  // 1/sqrt(128)
    float l0 = 1.f, l1 = 1.f;

    // ---------- scores^T = K·Q^T ; softmax ; P -> sX (waves 0-3, 32 s each) ----------
    if (w < 4) {
        const int s0 = w << 5;
        f32x4 sc[8][2];
        #pragma unroll
        for (int rt = 0; rt < 8; ++rt) { sc[rt][0] = FZ; sc[rt][1] = FZ; }
        #pragma unroll
        for (int kk = 0; kk < 4; ++kk) {
            const int k0 = kk * 32 + g * 8;
            bf16x8 q0 = *reinterpret_cast<const bf16x8*>(&sX[s0 + c][k0]);
            bf16x8 q1 = *reinterpret_cast<const bf16x8*>(&sX[s0 + 16 + c][k0]);
            #pragma unroll
            for (int rt = 0; rt < 8; ++rt) {
                bf16x8 akf = *reinterpret_cast<const bf16x8*>(&sKV[rt * 16 + c][k0]);
                sc[rt][0] = MFMA16(akf, q0, sc[rt][0]);
                sc[rt][1] = MFMA16(akf, q1, sc[rt][1]);
            }
        }
        #pragma unroll
        for (int ct = 0; ct < 2; ++ct) {
            float m = -3.0e38f;
            #pragma unroll
            for (int rt = 0; rt < 8; ++rt)
                #pragma unroll
                for (int r = 0; r < 4; ++r) m = fmaxf(m, sc[rt][ct][r]);
            m = fmaxf(m, __shfl_xor(m, 16));
            m = fmaxf(m, __shfl_xor(m, 32));
            float ls = 0.f, wsum = 0.f;
            #pragma unroll
            for (int rt = 0; rt < 8; ++rt) {
                #pragma unroll
                for (int r = 0; r < 4; ++r) {
                    float p = __expf((sc[rt][ct][r] - m) * rs);
                    sc[rt][ct][r] = p;
                    ls += p;
                    wsum += p * sTm[rt * 16 + g * 4 + r];
                }
            }
            ls   += __shfl_xor(ls, 16);   ls   += __shfl_xor(ls, 32);
            wsum += __shfl_xor(wsum, 16); wsum += __shfl_xor(wsum, 32);
            if (ct == 0) l0 = ls; else l1 = ls;
            if (g == 0)
                out[(size_t)67108864 + (size_t)bn * 128 + s0 + ct * 16 + c] = 1.0f - wsum / ls;
            #pragma unroll
            for (int rt = 0; rt < 8; ++rt) {
                bf16x4 pk;
                #pragma unroll
                for (int r = 0; r < 4; ++r) pk[r] = (bf16)sc[rt][ct][r];
                *reinterpret_cast<bf16x4*>(&sX[s0 + ct * 16 + c][rt * 16 + g * 4]) = pk;
            }
        }
    }
    __syncthreads();                      // #6: K reads done (all waves)

    // ---------- V (regs) -> sKV as V^T[h][t] (all 8 waves, col-split patches) ----------
    {
        #pragma unroll
        for (int ct = 0; ct < 4; ++ct)
            #pragma unroll
            for (int rt = 0; rt < 2; ++rt)
                *reinterpret_cast<bf16x4*>(&sKV[h0 + ct * 16 + c][r0 + rt * 16 + g * 4]) = vpk[rt][ct];
    }
    __syncthreads();                      // #7: V^T published

    if (w < 4) {
        const int s0 = w << 5;

        // ---------- rec^T[h][s] = V^T·P ; normalize ; rec -> sX own rows ----------
        {
            f32x4 rc[8][2];
            #pragma unroll
            for (int rt = 0; rt < 8; ++rt) { rc[rt][0] = FZ; rc[rt][1] = FZ; }
            #pragma unroll
            for (int kk = 0; kk < 4; ++kk) {
                const int k0 = kk * 32 + g * 8;
                bf16x8 p0 = *reinterpret_cast<const bf16x8*>(&sX[s0 + c][k0]);
                bf16x8 p1 = *reinterpret_cast<const bf16x8*>(&sX[s0 + 16 + c][k0]);
                #pragma unroll
                for (int rt = 0; rt < 8; ++rt) {
                    bf16x8 avf = *reinterpret_cast<const bf16x8*>(&sKV[rt * 16 + c][k0]);
                    rc[rt][0] = MFMA16(avf, p0, rc[rt][0]);
                    rc[rt][1] = MFMA16(avf, p1, rc[rt][1]);
                }
            }
            const float inv0 = __builtin_amdgcn_rcpf(l0);
            const float inv1 = __builtin_amdgcn_rcpf(l1);
            #pragma unroll
            for (int rt = 0; rt < 8; ++rt) {
                bf16x4 pk0, pk1;
                #pragma unroll
                for (int r = 0; r < 4; ++r) {
                    pk0[r] = (bf16)(rc[rt][0][r] * inv0);
                    pk1[r] = (bf16)(rc[rt][1][r] * inv1);
                }
                *reinterpret_cast<bf16x4*>(&sX[s0 + c][rt * 16 + g * 4]) = pk0;
                *reinterpret_cast<bf16x4*>(&sX[s0 + 16 + c][rt * 16 + g * 4]) = pk1;
            }
        }

        // ---------- out^T[ho][s] = Wo^T·rec^T + bo ; store f32 ----------
        {
            f32x4 oc[8][2];
            #pragma unroll
            for (int rt = 0; rt < 8; ++rt) { oc[rt][0] = FZ; oc[rt][1] = FZ; }
            #pragma unroll
            for (int kk = 0; kk < 4; ++kk) {
                const int k0 = kk * 32 + g * 8;
                bf16x8 e0 = *reinterpret_cast<const bf16x8*>(&sX[s0 + c][k0]);
                bf16x8 e1 = *reinterpret_cast<const bf16x8*>(&sX[s0 + 16 + c][k0]);
                #pragma unroll
                for (int rt = 0; rt < 8; ++rt) {
                    bf16x8 aw = ldw(&sW[0][0], rt * 16 + c, k0);
                    oc[rt][0] = MFMA16(aw, e0, oc[rt][0]);
                    oc[rt][1] = MFMA16(aw, e1, oc[rt][1]);
                }
            }
            float* outb = out + (size_t)bn * 16384;
            #pragma unroll
            for (int ct = 0; ct < 2; ++ct) {
                const int s = s0 + ct * 16 + c;
                #pragma unroll
                for (int rt = 0; rt < 8; ++rt) {
                    const int ho0 = rt * 16 + g * 4;
                    const float4 bo4 = *reinterpret_cast<const float4*>(bo + ho0);
                    float4 v;
                    v.x = oc[rt][ct][0] + bo4.x;
                    v.y = oc[rt][ct][1] + bo4.y;
                    v.z = oc[rt][ct][2] + bo4.z;
                    v.w = oc[rt][ct][3] + bo4.w;
                    *reinterpret_cast<float4*>(outb + s * 128 + ho0) = v;
                }
            }
        }
    }
}

extern "C" void kernel_launch(void* const* d_in, const int* in_sizes, int n_in,
                              void* d_out, int out_size, void* d_ws, size_t ws_size,
                              hipStream_t stream)
{
    (void)in_sizes; (void)n_in; (void)out_size; (void)ws_size;
    const float* xf     = (const float*)d_in[0];
    const float* ex     = (const float*)d_in[1];
    const int*   nf     = (const int*)d_in[2];
    const unsigned char* mask = (const unsigned char*)d_in[3];
    const float* W_in   = (const float*)d_in[4];
    const float* b_in   = (const float*)d_in[5];
    const float* W_t    = (const float*)d_in[6];
    const float* b_t    = (const float*)d_in[7];
    const float* E_node = (const float*)d_in[8];
    const float* W_q    = (const float*)d_in[9];
    const float* b_q    = (const float*)d_in[10];
    const float* W_k    = (const float*)d_in[11];
    const float* b_k    = (const float*)d_in[12];
    const float* W_v    = (const float*)d_in[13];
    const float* b_v    = (const float*)d_in[14];
    const float* W_o    = (const float*)d_in[15];
    const float* b_o    = (const float*)d_in[16];
    float* out = (float*)d_out;

    // ws layout: [0,163840) 5x bf16 128x128 transposed weights;
    //            [163840,1212416) biasT f32 [16][128][128] (t fastest);
    //            [1212416,1343488) npart f32 [256][128].
    bf16*  wsW    = (bf16*)d_ws;
    float* biasT  = (float*)((char*)d_ws + 163840);
    float* npart  = (float*)((char*)d_ws + 1212416);

    prep_weights<<<320, 256, 0, stream>>>(W_in, W_q, W_k, W_v, W_o, wsW);
    prep_npart<<<256, 128, 0, stream>>>(nf, E_node, W_in, npart);
    prep_bias<<<2048, 128, 0, stream>>>(ex, W_t, b_t, W_in, b_in, biasT);
    fused_main<<<4096, 512, 0, stream>>>(xf, mask, wsW, biasT, npart,
                                         b_q, b_k, b_v, b_o, out);
}

// Round 8
// 364.604 us; speedup vs baseline: 1.0356x; 1.0356x over previous
//
#include <hip/hip_runtime.h>
#include <hip/hip_bf16.h>
#include <stdint.h>

// TemporalAttention for MI355X (gfx950). B=16, N=256, T=128, H=128.
// R8: R6 base (8 waves, all-wave attention) + R7 projection col-split (32r x 64c
//     per wave) + SWAPPED operand order for G1/K/Q (A=W rows h, B=X cols t) so
//     epilogues write packed bf16x4 along h instead of 32 scalar b16 writes,
//     with float4 bias loads (biasT now [b][t][h]). V keeps original orientation
//     (packed along t into V^T). Q deferred via regs + barrier.

typedef __bf16 bf16;
typedef __bf16 bf16x4 __attribute__((ext_vector_type(4)));
typedef __bf16 bf16x8 __attribute__((ext_vector_type(8)));
typedef float  f32x4  __attribute__((ext_vector_type(4)));

#define MFMA16(a, b, c) __builtin_amdgcn_mfma_f32_16x16x32_bf16((a), (b), (c), 0, 0, 0)

__device__ __forceinline__ int allBytesNonzero(unsigned v) {
    return ((v - 0x01010101u) & ~v & 0x80808080u) == 0u;
}

__device__ __forceinline__ bf16x8 cvt8(const float* p) {
    float4 f0 = *reinterpret_cast<const float4*>(p);
    float4 f1 = *reinterpret_cast<const float4*>(p + 4);
    bf16x8 r;
    r[0] = (bf16)f0.x; r[1] = (bf16)f0.y; r[2] = (bf16)f0.z; r[3] = (bf16)f0.w;
    r[4] = (bf16)f1.x; r[5] = (bf16)f1.y; r[6] = (bf16)f1.z; r[7] = (bf16)f1.w;
    return r;
}

// branchless erf-GELU, A&S 7.1.26 (|err| < 1.5e-7)
__device__ __forceinline__ float gelu_erf(float v) {
    float x  = v * 0.70710678118654752f;
    float ax = fabsf(x);
    float t  = __builtin_amdgcn_rcpf(1.0f + 0.3275911f * ax);
    float p  = ((((1.061405429f * t - 1.453152027f) * t + 1.421413741f) * t
                 - 0.284496736f) * t + 0.254829592f) * t;
    float er = 1.0f - p * __expf(-ax * ax);
    er = copysignf(er, x);
    return 0.5f * v * (1.0f + er);
}

// Swizzled weight-fragment read from a 32KB LDS weight slot.
// Logical (row, k0..k0+7) lives at elem row*128 + (k0 ^ ((row&15)<<3)).
__device__ __forceinline__ bf16x8 ldw(const bf16* w, int row, int k0) {
    return *reinterpret_cast<const bf16x8*>(w + row * 128 + (k0 ^ ((row & 15) << 3)));
}

// ---- pre-kernel 1: transpose W1(=W_in[0:128]), Wq, Wk, Wv, Wo to bf16 [h][k] ----
__global__ void prep_weights(const float* __restrict__ W_in,
                             const float* __restrict__ Wq, const float* __restrict__ Wk,
                             const float* __restrict__ Wv, const float* __restrict__ Wo,
                             bf16* __restrict__ dst)
{
    int idx = blockIdx.x * 256 + threadIdx.x;
    if (idx >= 5 * 16384) return;
    int m = idx >> 14, r = idx & 16383;
    int h = r >> 7, k = r & 127;
    const float* src = (m == 0) ? W_in : (m == 1) ? Wq : (m == 2) ? Wk : (m == 3) ? Wv : Wo;
    dst[(m << 14) + h * 128 + k] = (bf16)src[k * 128 + h];  // dst[m][h][k] = W[k][h]
}

// ---- pre-kernel 2: npart[n][h] = E_node[nf[n]] @ W_in[256:384] (f32) ----
__global__ void prep_npart(const int* __restrict__ nf, const float* __restrict__ E_node,
                           const float* __restrict__ W_in, float* __restrict__ npart)
{
    int n = blockIdx.x, h = threadIdx.x;
    int node = nf[n];
    const float* e = E_node + node * 128;
    float acc = 0.f;
    for (int k = 0; k < 128; ++k) acc += e[k] * W_in[(256 + k) * 128 + h];
    npart[n * 128 + h] = acc;
}

// ---- pre-kernel 3: biasT[b][t][h] (h fastest for float4 epilogue loads) ----
__global__ void prep_bias(const float* __restrict__ ex, const float* __restrict__ W_t,
                          const float* __restrict__ b_t, const float* __restrict__ W_in,
                          const float* __restrict__ b_in, float* __restrict__ biasT)
{
    const int bt = blockIdx.x;          // b*128 + t
    const int t = bt & 127;
    const int h = threadIdx.x;
    __shared__ float te[128];
    float v = b_t[h];
    const float* exr = ex + (size_t)bt * 32;
    for (int d = 0; d < 32; ++d) v += exr[d] * W_t[d * 128 + h];
    te[h] = v;
    __syncthreads();
    float acc = b_in[h];
    const float ninv = -9.210340371976184f / 128.0f;   // -ln(10000)/H
    for (int j = 0; j < 64; ++j) {
        float div = expf((float)(2 * j) * ninv);
        float ang = (float)t * div;
        acc += sinf(ang) * W_in[(2 * j) * 128 + h] + cosf(ang) * W_in[(2 * j + 1) * 128 + h];
    }
    for (int k = 0; k < 128; ++k) acc += te[k] * W_in[(128 + k) * 128 + h];
    biasT[(size_t)bt * 128 + h] = acc;   // [b][t][h]
}

// ---- main fused kernel: 1 block per (b,n), 8 waves ----
// Projections: wave (wr=w&3, wc=w>>2) owns rows t in [32wr,+32) x cols h in [64wc,+64).
//   G1/K/Q swapped: MFMA(A=W-frag rows h, B=X-frag cols t) -> C: col=t, row=h
//     (4 consecutive h per lane -> packed bf16x4 epilogue writes, float4 bias).
//   V original: MFMA(A=X rows t, B=W cols h) -> C: col=h, row=t (packed along t).
// Attention: all 8 waves, wave w owns s in [16w,16w+16) (R6-proven code).
// MFMA 16x16x32: A row=lane&15,k=(lane>>4)*8+j; B col=lane&15; C/D col=lane&15,row=(lane>>4)*4+reg.
#define STAGE_ISSUE(SRC)                                                        \
    {                                                                           \
        _Pragma("unroll")                                                       \
        for (int i = 0; i < 4; ++i)                                             \
            stg[i] = *reinterpret_cast<const bf16x8*>((SRC) + (tid + i * 512) * 8); \
    }
#define STAGE_WRITE(BUF)                                                        \
    {                                                                           \
        _Pragma("unroll")                                                       \
        for (int i = 0; i < 4; ++i) {                                           \
            int m_ = tid + i * 512;                                             \
            int row_ = m_ >> 4, slot_ = m_ & 15;                                \
            *reinterpret_cast<bf16x8*>(&sW[BUF][row_ * 128 + 8 * (slot_ ^ (row_ & 15))]) = stg[i]; \
        }                                                                       \
    }

__global__ __launch_bounds__(512, 2) void fused_main(
    const float* __restrict__ xf, const unsigned char* __restrict__ mask,
    const bf16* __restrict__ wsW, const float* __restrict__ biasT,
    const float* __restrict__ npart,
    const float* __restrict__ bq, const float* __restrict__ bk,
    const float* __restrict__ bv, const float* __restrict__ bo,
    float* __restrict__ out)
{
    const bf16* W1T = wsW;
    const bf16* WqT = wsW + 16384;
    const bf16* WkT = wsW + 32768;
    const bf16* WvT = wsW + 49152;
    const bf16* WoT = wsW + 65536;

    __shared__ bf16 sX[128][136];    // X -> Q -> P -> rec
    __shared__ bf16 sKV[128][136];   // K[t][h] -> V^T[h][t]
    __shared__ bf16 sW[2][16384];    // double-buffered weight slots (XOR-swizzled)
    __shared__ float sTm[128];

    const int bn = blockIdx.x;
    const int b  = bn >> 8;
    const int n  = bn & 255;
    const int tid  = (int)threadIdx.x;
    const int w    = tid >> 6;      // 0..7
    const int lane = tid & 63;
    const int c = lane & 15;
    const int g = lane >> 4;
    const int wr = w & 3;           // projection row-group
    const int wc = w >> 2;          // projection col-group
    const int r0 = wr << 5;         // row base (t), 32 rows
    const int h0 = wc << 6;         // col base (h), 64 cols

    const f32x4 FZ = {0.f, 0.f, 0.f, 0.f};
    bf16x8 stg[4];

    // ---- t_mask[t] = all(mask[b,n,t,:]) ----
    if (tid < 128) {
        const uint4* mp = reinterpret_cast<const uint4*>(mask + ((size_t)bn * 128 + tid) * 128);
        int ok = 1;
        #pragma unroll
        for (int i = 0; i < 8; ++i) {
            uint4 u = mp[i];
            ok &= allBytesNonzero(u.x) & allBytesNonzero(u.y)
                & allBytesNonzero(u.z) & allBytesNonzero(u.w);
        }
        sTm[tid] = ok ? 1.0f : 0.0f;
    }

    // ---- stage W1 -> sW[0]; prefetch xf B-fragments (cols t = wave's 2 t-tiles) ----
    STAGE_ISSUE(W1T);
    bf16x8 af[2][4];
    {
        const float* xfb = xf + (size_t)bn * 16384;
        #pragma unroll
        for (int tt = 0; tt < 2; ++tt)
            #pragma unroll
            for (int kk = 0; kk < 4; ++kk)
                af[tt][kk] = cvt8(xfb + (r0 + tt * 16 + c) * 128 + kk * 32 + g * 8);
    }
    STAGE_WRITE(0);
    __syncthreads();                      // #1: sW[0]=W1

    // ---------- G1 (swapped): X = gelu(xf@W1 + bias + npart) -> sX[t][h], packed ----------
    STAGE_ISSUE(WkT);
    {
        f32x4 acc[2][4];                  // [t-tile][h-tile]
        #pragma unroll
        for (int tt = 0; tt < 2; ++tt)
            #pragma unroll
            for (int ht = 0; ht < 4; ++ht) acc[tt][ht] = FZ;
        #pragma unroll
        for (int kk = 0; kk < 4; ++kk) {
            const int k0 = kk * 32 + g * 8;
            #pragma unroll
            for (int ht = 0; ht < 4; ++ht) {
                bf16x8 aw = ldw(&sW[0][0], h0 + ht * 16 + c, k0);   // A: W rows h
                acc[0][ht] = MFMA16(aw, af[0][kk], acc[0][ht]);
                acc[1][ht] = MFMA16(aw, af[1][kk], acc[1][ht]);
            }
        }
        const float* biasB = biasT + (size_t)b * 16384;   // [t][h]
        const float* npRow = npart + n * 128;
        #pragma unroll
        for (int tt = 0; tt < 2; ++tt) {
            const int t = r0 + tt * 16 + c;
            #pragma unroll
            for (int ht = 0; ht < 4; ++ht) {
                const int ha = h0 + ht * 16 + g * 4;
                const float4 bb = *reinterpret_cast<const float4*>(biasB + t * 128 + ha);
                const float4 np4 = *reinterpret_cast<const float4*>(npRow + ha);
                const float bbr[4] = {bb.x + np4.x, bb.y + np4.y, bb.z + np4.z, bb.w + np4.w};
                bf16x4 pk;
                #pragma unroll
                for (int r = 0; r < 4; ++r)
                    pk[r] = (bf16)gelu_erf(acc[tt][ht][r] + bbr[r]);
                *reinterpret_cast<bf16x4*>(&sX[t][ha]) = pk;
            }
        }
    }
    STAGE_WRITE(1);
    __syncthreads();                      // #2: sW[1]=Wk, sX=X

    // ---------- K (swapped): K = X@Wk + bk -> sKV[t][h], packed ----------
    STAGE_ISSUE(WvT);
    {
        f32x4 acc[2][4];
        #pragma unroll
        for (int tt = 0; tt < 2; ++tt)
            #pragma unroll
            for (int ht = 0; ht < 4; ++ht) acc[tt][ht] = FZ;
        #pragma unroll
        for (int kk = 0; kk < 4; ++kk) {
            const int k0 = kk * 32 + g * 8;
            bf16x8 x0 = *reinterpret_cast<const bf16x8*>(&sX[r0 + c][k0]);        // B: X cols t
            bf16x8 x1 = *reinterpret_cast<const bf16x8*>(&sX[r0 + 16 + c][k0]);
            #pragma unroll
            for (int ht = 0; ht < 4; ++ht) {
                bf16x8 aw = ldw(&sW[1][0], h0 + ht * 16 + c, k0);
                acc[0][ht] = MFMA16(aw, x0, acc[0][ht]);
                acc[1][ht] = MFMA16(aw, x1, acc[1][ht]);
            }
        }
        #pragma unroll
        for (int tt = 0; tt < 2; ++tt) {
            const int t = r0 + tt * 16 + c;
            #pragma unroll
            for (int ht = 0; ht < 4; ++ht) {
                const int ha = h0 + ht * 16 + g * 4;
                const float4 bk4 = *reinterpret_cast<const float4*>(bk + ha);
                const float bkr[4] = {bk4.x, bk4.y, bk4.z, bk4.w};
                bf16x4 pk;
                #pragma unroll
                for (int r = 0; r < 4; ++r)
                    pk[r] = (bf16)(acc[tt][ht][r] + bkr[r]);
                *reinterpret_cast<bf16x4*>(&sKV[t][ha]) = pk;
            }
        }
    }
    STAGE_WRITE(0);                       // Wv -> sW[0]
    __syncthreads();                      // #3

    // ---------- V (original): V = X@Wv + bv -> vpk regs (packed along t) ----------
    bf16x4 vpk[2][4];                     // [t-tile][h-tile]
    STAGE_ISSUE(WqT);
    {
        f32x4 acc[2][4];
        #pragma unroll
        for (int tt = 0; tt < 2; ++tt)
            #pragma unroll
            for (int ht = 0; ht < 4; ++ht) acc[tt][ht] = FZ;
        #pragma unroll
        for (int kk = 0; kk < 4; ++kk) {
            const int k0 = kk * 32 + g * 8;
            bf16x8 x0 = *reinterpret_cast<const bf16x8*>(&sX[r0 + c][k0]);        // A: X rows t
            bf16x8 x1 = *reinterpret_cast<const bf16x8*>(&sX[r0 + 16 + c][k0]);
            #pragma unroll
            for (int ht = 0; ht < 4; ++ht) {
                bf16x8 bw = ldw(&sW[0][0], h0 + ht * 16 + c, k0);  // B: W cols h
                acc[0][ht] = MFMA16(x0, bw, acc[0][ht]);
                acc[1][ht] = MFMA16(x1, bw, acc[1][ht]);
            }
        }
        #pragma unroll
        for (int ht = 0; ht < 4; ++ht) {
            const float bvv = bv[h0 + ht * 16 + c];
            #pragma unroll
            for (int tt = 0; tt < 2; ++tt)
                #pragma unroll
                for (int r = 0; r < 4; ++r)
                    vpk[tt][ht][r] = (bf16)(acc[tt][ht][r] + bvv);
        }
    }
    STAGE_WRITE(1);                       // Wq -> sW[1]
    __syncthreads();                      // #4

    // ---------- Q (swapped): Q = X@Wq + bq -> regs, write deferred ----------
    f32x4 aq[2][4];
    STAGE_ISSUE(WoT);
    {
        #pragma unroll
        for (int tt = 0; tt < 2; ++tt)
            #pragma unroll
            for (int ht = 0; ht < 4; ++ht) aq[tt][ht] = FZ;
        #pragma unroll
        for (int kk = 0; kk < 4; ++kk) {
            const int k0 = kk * 32 + g * 8;
            bf16x8 x0 = *reinterpret_cast<const bf16x8*>(&sX[r0 + c][k0]);
            bf16x8 x1 = *reinterpret_cast<const bf16x8*>(&sX[r0 + 16 + c][k0]);
            #pragma unroll
            for (int ht = 0; ht < 4; ++ht) {
                bf16x8 aw = ldw(&sW[1][0], h0 + ht * 16 + c, k0);
                aq[0][ht] = MFMA16(aw, x0, aq[0][ht]);
                aq[1][ht] = MFMA16(aw, x1, aq[1][ht]);
            }
        }
    }
    STAGE_WRITE(0);                       // Wo -> sW[0]
    __syncthreads();                      // #5a: all X reads done, Wo published

    {
        #pragma unroll
        for (int tt = 0; tt < 2; ++tt) {
            const int t = r0 + tt * 16 + c;
            #pragma unroll
            for (int ht = 0; ht < 4; ++ht) {
                const int ha = h0 + ht * 16 + g * 4;
                const float4 bq4 = *reinterpret_cast<const float4*>(bq + ha);
                const float bqr[4] = {bq4.x, bq4.y, bq4.z, bq4.w};
                bf16x4 pk;
                #pragma unroll
                for (int r = 0; r < 4; ++r)
                    pk[r] = (bf16)(aq[tt][ht][r] + bqr[r]);
                *reinterpret_cast<bf16x4*>(&sX[t][ha]) = pk;
            }
        }
    }
    __syncthreads();                      // #5b: Q published

    const float rs = 0.08838834764831845f;  // 1/sqrt(128)
    float l0 = 1.f;
    const int s0 = w << 4;                // attention: 16 s-rows per wave

    // ---------- scores^T[t][s] = K·Q^T ; softmax over t ; P -> sX own rows ----------
    {
        f32x4 sc[8];
        #pragma unroll
        for (int rt = 0; rt < 8; ++rt) sc[rt] = FZ;
        #pragma unroll
        for (int kk = 0; kk < 4; ++kk) {
            const int k0 = kk * 32 + g * 8;
            bf16x8 q0 = *reinterpret_cast<const bf16x8*>(&sX[s0 + c][k0]);
            #pragma unroll
            for (int rt = 0; rt < 8; ++rt) {
                bf16x8 akf = *reinterpret_cast<const bf16x8*>(&sKV[rt * 16 + c][k0]);
                sc[rt] = MFMA16(akf, q0, sc[rt]);
            }
        }
        float m = -3.0e38f;
        #pragma unroll
        for (int rt = 0; rt < 8; ++rt)
            #pragma unroll
            for (int r = 0; r < 4; ++r) m = fmaxf(m, sc[rt][r]);
        m = fmaxf(m, __shfl_xor(m, 16));
        m = fmaxf(m, __shfl_xor(m, 32));
        float ls = 0.f, wsum = 0.f;
        #pragma unroll
        for (int rt = 0; rt < 8; ++rt) {
            #pragma unroll
            for (int r = 0; r < 4; ++r) {
                float p = __expf((sc[rt][r] - m) * rs);
                sc[rt][r] = p;
                ls += p;
                wsum += p * sTm[rt * 16 + g * 4 + r];
            }
        }
        ls   += __shfl_xor(ls, 16);   ls   += __shfl_xor(ls, 32);
        wsum += __shfl_xor(wsum, 16); wsum += __shfl_xor(wsum, 32);
        l0 = ls;
        if (g == 0)
            out[(size_t)67108864 + (size_t)bn * 128 + s0 + c] = 1.0f - wsum / ls;
        #pragma unroll
        for (int rt = 0; rt < 8; ++rt) {
            bf16x4 pk;
            #pragma unroll
            for (int r = 0; r < 4; ++r) pk[r] = (bf16)sc[rt][r];
            *reinterpret_cast<bf16x4*>(&sX[s0 + c][rt * 16 + g * 4]) = pk;
        }
    }
    __syncthreads();                      // #6: K reads done

    // ---------- V (regs) -> sKV as V^T[h][t] ----------
    {
        #pragma unroll
        for (int ht = 0; ht < 4; ++ht)
            #pragma unroll
            for (int tt = 0; tt < 2; ++tt)
                *reinterpret_cast<bf16x4*>(&sKV[h0 + ht * 16 + c][r0 + tt * 16 + g * 4]) = vpk[tt][ht];
    }
    __syncthreads();                      // #7: V^T published

    // ---------- rec^T[h][s] = V^T·P ; normalize ; rec -> sX own rows ----------
    {
        f32x4 rc[8];
        #pragma unroll
        for (int rt = 0; rt < 8; ++rt) rc[rt] = FZ;
        #pragma unroll
        for (int kk = 0; kk < 4; ++kk) {
            const int k0 = kk * 32 + g * 8;
            bf16x8 p0 = *reinterpret_cast<const bf16x8*>(&sX[s0 + c][k0]);
            #pragma unroll
            for (int rt = 0; rt < 8; ++rt) {
                bf16x8 avf = *reinterpret_cast<const bf16x8*>(&sKV[rt * 16 + c][k0]);
                rc[rt] = MFMA16(avf, p0, rc[rt]);
            }
        }
        const float inv0 = __builtin_amdgcn_rcpf(l0);
        #pragma unroll
        for (int rt = 0; rt < 8; ++rt) {
            bf16x4 pk0;
            #pragma unroll
            for (int r = 0; r < 4; ++r) pk0[r] = (bf16)(rc[rt][r] * inv0);
            *reinterpret_cast<bf16x4*>(&sX[s0 + c][rt * 16 + g * 4]) = pk0;
        }
    }

    // ---------- out^T[ho][s] = Wo^T·rec^T + bo ; store f32 ----------
    {
        f32x4 oc[8];
        #pragma unroll
        for (int rt = 0; rt < 8; ++rt) oc[rt] = FZ;
        #pragma unroll
        for (int kk = 0; kk < 4; ++kk) {
            const int k0 = kk * 32 + g * 8;
            bf16x8 e0 = *reinterpret_cast<const bf16x8*>(&sX[s0 + c][k0]);
            #pragma unroll
            for (int rt = 0; rt < 8; ++rt) {
                bf16x8 aw = ldw(&sW[0][0], rt * 16 + c, k0);
                oc[rt] = MFMA16(aw, e0, oc[rt]);
            }
        }
        float* outb = out + (size_t)bn * 16384;
        const int s = s0 + c;
        #pragma unroll
        for (int rt = 0; rt < 8; ++rt) {
            const int ho0 = rt * 16 + g * 4;
            const float4 bo4 = *reinterpret_cast<const float4*>(bo + ho0);
            float4 v;
            v.x = oc[rt][0] + bo4.x;
            v.y = oc[rt][1] + bo4.y;
            v.z = oc[rt][2] + bo4.z;
            v.w = oc[rt][3] + bo4.w;
            *reinterpret_cast<float4*>(outb + s * 128 + ho0) = v;
        }
    }
}

extern "C" void kernel_launch(void* const* d_in, const int* in_sizes, int n_in,
                              void* d_out, int out_size, void* d_ws, size_t ws_size,
                              hipStream_t stream)
{
    (void)in_sizes; (void)n_in; (void)out_size; (void)ws_size;
    const float* xf     = (const float*)d_in[0];
    const float* ex     = (const float*)d_in[1];
    const int*   nf     = (const int*)d_in[2];
    const unsigned char* mask = (const unsigned char*)d_in[3];
    const float* W_in   = (const float*)d_in[4];
    const float* b_in   = (const float*)d_in[5];
    const float* W_t    = (const float*)d_in[6];
    const float* b_t    = (const float*)d_in[7];
    const float* E_node = (const float*)d_in[8];
    const float* W_q    = (const float*)d_in[9];
    const float* b_q    = (const float*)d_in[10];
    const float* W_k    = (const float*)d_in[11];
    const float* b_k    = (const float*)d_in[12];
    const float* W_v    = (const float*)d_in[13];
    const float* b_v    = (const float*)d_in[14];
    const float* W_o    = (const float*)d_in[15];
    const float* b_o    = (const float*)d_in[16];
    float* out = (float*)d_out;

    // ws layout: [0,163840) 5x bf16 128x128 transposed weights;
    //            [163840,1212416) biasT f32 [16][128][128] (h fastest);
    //            [1212416,1343488) npart f32 [256][128].
    bf16*  wsW    = (bf16*)d_ws;
    float* biasT  = (float*)((char*)d_ws + 163840);
    float* npart  = (float*)((char*)d_ws + 1212416);

    prep_weights<<<320, 256, 0, stream>>>(W_in, W_q, W_k, W_v, W_o, wsW);
    prep_npart<<<256, 128, 0, stream>>>(nf, E_node, W_in, npart);
    prep_bias<<<2048, 128, 0, stream>>>(ex, W_t, b_t, W_in, b_in, biasT);
    fused_main<<<4096, 512, 0, stream>>>(xf, mask, wsW, biasT, npart,
                                         b_q, b_k, b_v, b_o, out);
}

// Round 9
// 317.897 us; speedup vs baseline: 1.1878x; 1.1469x over previous
//
#include <hip/hip_runtime.h>
#include <hip/hip_bf16.h>
#include <stdint.h>

// TemporalAttention for MI355X (gfx950). B=16, N=256, T=128, H=128.
// R9: ALGEBRAIC FUSION, 7 GEMMs -> 5 per (b,n):
//   scores = Q.K^T = X G X^T + (X.v)[t] + const(s)  [const drops in softmax]
//     G = Wq Wk^T, v = Wk bq  (precomputed)  -> no Q projection, no K bias
//   out = A (X Wv) Wo + bo = A (X N) + bias2  [softmax rows sum to 1]
//     N = Wv Wo, bias2 = Wo^T bv + bo         -> no out projection
//   Phases: G1 -> Y=X G^T -> V2=X N -> scores(Y.X^T+w) -> PV(+bias2).
//   5 barriers, 3 weight stagings (W1, G, N), X/P handoffs wave-private.

typedef __bf16 bf16;
typedef __bf16 bf16x4 __attribute__((ext_vector_type(4)));
typedef __bf16 bf16x8 __attribute__((ext_vector_type(8)));
typedef float  f32x4  __attribute__((ext_vector_type(4)));

#define MFMA16(a, b, c) __builtin_amdgcn_mfma_f32_16x16x32_bf16((a), (b), (c), 0, 0, 0)

__device__ __forceinline__ int allBytesNonzero(unsigned v) {
    return ((v - 0x01010101u) & ~v & 0x80808080u) == 0u;
}

__device__ __forceinline__ bf16x8 cvt8(const float* p) {
    float4 f0 = *reinterpret_cast<const float4*>(p);
    float4 f1 = *reinterpret_cast<const float4*>(p + 4);
    bf16x8 r;
    r[0] = (bf16)f0.x; r[1] = (bf16)f0.y; r[2] = (bf16)f0.z; r[3] = (bf16)f0.w;
    r[4] = (bf16)f1.x; r[5] = (bf16)f1.y; r[6] = (bf16)f1.z; r[7] = (bf16)f1.w;
    return r;
}

// branchless erf-GELU, A&S 7.1.26 (|err| < 1.5e-7)
__device__ __forceinline__ float gelu_erf(float v) {
    float x  = v * 0.70710678118654752f;
    float ax = fabsf(x);
    float t  = __builtin_amdgcn_rcpf(1.0f + 0.3275911f * ax);
    float p  = ((((1.061405429f * t - 1.453152027f) * t + 1.421413741f) * t
                 - 0.284496736f) * t + 0.254829592f) * t;
    float er = 1.0f - p * __expf(-ax * ax);
    er = copysignf(er, x);
    return 0.5f * v * (1.0f + er);
}

// Swizzled weight-fragment read from a 32KB LDS weight slot.
// Logical (row, k0..k0+7) lives at elem row*128 + (k0 ^ ((row&15)<<3)).
__device__ __forceinline__ bf16x8 ldw(const bf16* w, int row, int k0) {
    return *reinterpret_cast<const bf16x8*>(w + row * 128 + (k0 ^ ((row & 15) << 3)));
}

// ---- pre-kernel 1: W1T[h][k] = W_in[k][h] (bf16) ----
__global__ void prep_weights(const float* __restrict__ W_in, bf16* __restrict__ dst)
{
    int idx = blockIdx.x * 256 + threadIdx.x;   // 64 blocks
    int h = idx >> 7, k = idx & 127;
    dst[h * 128 + k] = (bf16)W_in[k * 128 + h];
}

// ---- pre-kernel 2: G = Wq @ Wk^T -> mstore[a][b]; v = Wk @ bq ----
__global__ void prep_G(const float* __restrict__ Wq, const float* __restrict__ Wk,
                       const float* __restrict__ bq, bf16* __restrict__ mstore,
                       float* __restrict__ vvec)
{
    const int a = blockIdx.x, bb = threadIdx.x;
    __shared__ float wqa[128];
    wqa[bb] = Wq[a * 128 + bb];
    __syncthreads();
    float acc = 0.f;
    for (int k = 0; k < 128; ++k) acc += wqa[k] * Wk[bb * 128 + k];
    mstore[a * 128 + bb] = (bf16)acc;
    if (a == 0) {
        float av = 0.f;
        for (int j = 0; j < 128; ++j) av += Wk[bb * 128 + j] * bq[j];
        vvec[bb] = av;
    }
}

// ---- pre-kernel 3: N = Wv @ Wo -> nstore[h2][h] (=N[h][h2]); bias2 = Wo^T bv + bo ----
__global__ void prep_N(const float* __restrict__ Wv, const float* __restrict__ Wo,
                       const float* __restrict__ bv, const float* __restrict__ bo,
                       bf16* __restrict__ nstore, float* __restrict__ bias2)
{
    const int h = blockIdx.x, h2 = threadIdx.x;
    __shared__ float wvh[128];
    wvh[h2] = Wv[h * 128 + h2];
    __syncthreads();
    float acc = 0.f;
    for (int j = 0; j < 128; ++j) acc += wvh[j] * Wo[j * 128 + h2];
    nstore[h2 * 128 + h] = (bf16)acc;           // transposed store: [h2][h]
    if (h == 0) {
        float b2 = 0.f;
        for (int j = 0; j < 128; ++j) b2 += bv[j] * Wo[j * 128 + h2];
        bias2[h2] = b2 + bo[h2];
    }
}

// ---- pre-kernel 4: npart[n][h] = E_node[nf[n]] @ W_in[256:384] (f32) ----
__global__ void prep_npart(const int* __restrict__ nf, const float* __restrict__ E_node,
                           const float* __restrict__ W_in, float* __restrict__ npart)
{
    int n = blockIdx.x, h = threadIdx.x;
    int node = nf[n];
    const float* e = E_node + node * 128;
    float acc = 0.f;
    for (int k = 0; k < 128; ++k) acc += e[k] * W_in[(256 + k) * 128 + h];
    npart[n * 128 + h] = acc;
}

// ---- pre-kernel 5: biasT[b][t][h] (h fastest) ----
__global__ void prep_bias(const float* __restrict__ ex, const float* __restrict__ W_t,
                          const float* __restrict__ b_t, const float* __restrict__ W_in,
                          const float* __restrict__ b_in, float* __restrict__ biasT)
{
    const int bt = blockIdx.x;          // b*128 + t
    const int t = bt & 127;
    const int h = threadIdx.x;
    __shared__ float te[128];
    float v = b_t[h];
    const float* exr = ex + (size_t)bt * 32;
    for (int d = 0; d < 32; ++d) v += exr[d] * W_t[d * 128 + h];
    te[h] = v;
    __syncthreads();
    float acc = b_in[h];
    const float ninv = -9.210340371976184f / 128.0f;   // -ln(10000)/H
    for (int j = 0; j < 64; ++j) {
        float div = expf((float)(2 * j) * ninv);
        float ang = (float)t * div;
        acc += sinf(ang) * W_in[(2 * j) * 128 + h] + cosf(ang) * W_in[(2 * j + 1) * 128 + h];
    }
    for (int k = 0; k < 128; ++k) acc += te[k] * W_in[(128 + k) * 128 + h];
    biasT[(size_t)bt * 128 + h] = acc;   // [b][t][h]
}

// ---- main fused kernel: 1 block per (b,n), 8 waves, wave w owns rows [16w,16w+16) ----
// MFMA 16x16x32: A row=lane&15,k=(lane>>4)*8+j; B col=lane&15,k=(lane>>4)*8+j;
// C/D col=lane&15, row=(lane>>4)*4+reg.
// Swapped phases (G1, Y): D[row][col] with row along the staged matrix's rows,
// col = t -> lane holds 4 consecutive output-features for fixed t (packed writes).
#define STAGE_ISSUE(SRC)                                                        \
    {                                                                           \
        _Pragma("unroll")                                                       \
        for (int i = 0; i < 4; ++i)                                             \
            stg[i] = *reinterpret_cast<const bf16x8*>((SRC) + (tid + i * 512) * 8); \
    }
#define STAGE_WRITE(BUF)                                                        \
    {                                                                           \
        _Pragma("unroll")                                                       \
        for (int i = 0; i < 4; ++i) {                                           \
            int m_ = tid + i * 512;                                             \
            int row_ = m_ >> 4, slot_ = m_ & 15;                                \
            *reinterpret_cast<bf16x8*>(&sW[BUF][row_ * 128 + 8 * (slot_ ^ (row_ & 15))]) = stg[i]; \
        }                                                                       \
    }

__global__ __launch_bounds__(512, 2) void fused_main(
    const float* __restrict__ xf, const unsigned char* __restrict__ mask,
    const bf16* __restrict__ wsW, const float* __restrict__ biasT,
    const float* __restrict__ npart, const float* __restrict__ vvec,
    const float* __restrict__ bias2, float* __restrict__ out)
{
    const bf16* W1T = wsW;
    const bf16* Mst = wsW + 16384;
    const bf16* Nst = wsW + 32768;

    __shared__ bf16 sX[128][136];    // X -> P (wave-private row transitions)
    __shared__ bf16 sKV[128][136];   // Y[t][a] -> V2^T[h2][t]
    __shared__ bf16 sW[2][16384];    // double-buffered weight slots (XOR-swizzled)
    __shared__ __align__(16) float sTm[128];
    __shared__ __align__(16) float sWt[128];

    const int bn = blockIdx.x;
    const int b  = bn >> 8;
    const int n  = bn & 255;
    const int tid  = (int)threadIdx.x;
    const int w    = tid >> 6;      // 0..7
    const int lane = tid & 63;
    const int c = lane & 15;
    const int g = lane >> 4;
    const int s0 = w << 4;          // 16 rows per wave

    const f32x4 FZ = {0.f, 0.f, 0.f, 0.f};
    bf16x8 stg[4];

    // ---- t_mask[t] = all(mask[b,n,t,:]) ----
    if (tid < 128) {
        const uint4* mp = reinterpret_cast<const uint4*>(mask + ((size_t)bn * 128 + tid) * 128);
        int ok = 1;
        #pragma unroll
        for (int i = 0; i < 8; ++i) {
            uint4 u = mp[i];
            ok &= allBytesNonzero(u.x) & allBytesNonzero(u.y)
                & allBytesNonzero(u.z) & allBytesNonzero(u.w);
        }
        sTm[tid] = ok ? 1.0f : 0.0f;
    }

    // ---- stage W1 -> sW[0]; prefetch xf fragments (col=t=s0+c, k=feature) ----
    STAGE_ISSUE(W1T);
    bf16x8 af[4];
    {
        const float* xfb = xf + (size_t)bn * 16384;
        #pragma unroll
        for (int kk = 0; kk < 4; ++kk)
            af[kk] = cvt8(xfb + (s0 + c) * 128 + kk * 32 + g * 8);
    }
    STAGE_WRITE(0);
    __syncthreads();                      // #1: sW[0]=W1

    // ---------- G1 (swapped): X = gelu(xf@W1 + biasT + npart) -> sX[t][h], packed ----------
    STAGE_ISSUE(Mst);
    {
        f32x4 acc[8];
        #pragma unroll
        for (int ht = 0; ht < 8; ++ht) acc[ht] = FZ;
        #pragma unroll
        for (int kk = 0; kk < 4; ++kk) {
            const int k0 = kk * 32 + g * 8;
            #pragma unroll
            for (int ht = 0; ht < 8; ++ht) {
                bf16x8 aw = ldw(&sW[0][0], ht * 16 + c, k0);
                acc[ht] = MFMA16(aw, af[kk], acc[ht]);
            }
        }
        const float* biasB = biasT + (size_t)b * 16384;   // [t][h]
        const float* npRow = npart + n * 128;
        const int t = s0 + c;
        #pragma unroll
        for (int ht = 0; ht < 8; ++ht) {
            const int hb = ht * 16 + g * 4;
            const float4 bb  = *reinterpret_cast<const float4*>(biasB + t * 128 + hb);
            const float4 np4 = *reinterpret_cast<const float4*>(npRow + hb);
            const float bbr[4] = {bb.x + np4.x, bb.y + np4.y, bb.z + np4.z, bb.w + np4.w};
            bf16x4 pk;
            #pragma unroll
            for (int r = 0; r < 4; ++r)
                pk[r] = (bf16)gelu_erf(acc[ht][r] + bbr[r]);
            *reinterpret_cast<bf16x4*>(&sX[t][hb]) = pk;
        }
    }
    STAGE_WRITE(1);                       // G -> sW[1]
    // X fragment readback (wave-private rows; lgkmcnt orders within wave)
    bf16x8 xb[4];
    #pragma unroll
    for (int kk = 0; kk < 4; ++kk)
        xb[kk] = *reinterpret_cast<const bf16x8*>(&sX[s0 + c][kk * 32 + g * 8]);
    __syncthreads();                      // #2: sW[1]=G published

    // ---------- Y = X @ G^T (swapped) -> sKV[t][a]; w[t] = X[t].v -> sWt ----------
    STAGE_ISSUE(Nst);
    {
        f32x4 acc[8];
        #pragma unroll
        for (int ht = 0; ht < 8; ++ht) acc[ht] = FZ;
        #pragma unroll
        for (int kk = 0; kk < 4; ++kk) {
            const int k0 = kk * 32 + g * 8;
            #pragma unroll
            for (int ht = 0; ht < 8; ++ht) {
                bf16x8 aw = ldw(&sW[1][0], ht * 16 + c, k0);
                acc[ht] = MFMA16(aw, xb[kk], acc[ht]);
            }
        }
        const int t = s0 + c;
        #pragma unroll
        for (int ht = 0; ht < 8; ++ht) {
            bf16x4 pk;
            #pragma unroll
            for (int r = 0; r < 4; ++r) pk[r] = (bf16)acc[ht][r];
            *reinterpret_cast<bf16x4*>(&sKV[t][ht * 16 + g * 4]) = pk;
        }
        // w[t] = dot(X[t], v)
        float wd = 0.f;
        #pragma unroll
        for (int kk = 0; kk < 4; ++kk) {
            const float4 vA = *reinterpret_cast<const float4*>(vvec + kk * 32 + g * 8);
            const float4 vB = *reinterpret_cast<const float4*>(vvec + kk * 32 + g * 8 + 4);
            wd += (float)xb[kk][0] * vA.x + (float)xb[kk][1] * vA.y
                + (float)xb[kk][2] * vA.z + (float)xb[kk][3] * vA.w
                + (float)xb[kk][4] * vB.x + (float)xb[kk][5] * vB.y
                + (float)xb[kk][6] * vB.z + (float)xb[kk][7] * vB.w;
        }
        wd += __shfl_xor(wd, 16);
        wd += __shfl_xor(wd, 32);
        if (g == 0) sWt[t] = wd;
    }
    STAGE_WRITE(0);                       // N -> sW[0] (W1 dead)
    __syncthreads();                      // #3: Y, sWt, N published

    // ---------- V2 = X @ N (normal) -> vpk regs (packed along t) ----------
    bf16x4 vpk[8];
    {
        f32x4 acc[8];
        #pragma unroll
        for (int ct = 0; ct < 8; ++ct) acc[ct] = FZ;
        #pragma unroll
        for (int kk = 0; kk < 4; ++kk) {
            const int k0 = kk * 32 + g * 8;
            #pragma unroll
            for (int ct = 0; ct < 8; ++ct) {
                bf16x8 bw = ldw(&sW[0][0], ct * 16 + c, k0);
                acc[ct] = MFMA16(xb[kk], bw, acc[ct]);
            }
        }
        #pragma unroll
        for (int ct = 0; ct < 8; ++ct)
            #pragma unroll
            for (int r = 0; r < 4; ++r)
                vpk[ct][r] = (bf16)acc[ct][r];
    }

    const float rs = 0.08838834764831845f;  // 1/sqrt(128)
    float l0 = 1.f;

    // ---------- scores^T[t][s] = Y·X^T + w[t] ; softmax over t ; P -> sX own rows ----------
    {
        f32x4 sc[8];
        #pragma unroll
        for (int rt = 0; rt < 8; ++rt) sc[rt] = FZ;
        #pragma unroll
        for (int kk = 0; kk < 4; ++kk) {
            const int k0 = kk * 32 + g * 8;
            #pragma unroll
            for (int rt = 0; rt < 8; ++rt) {
                bf16x8 ay = *reinterpret_cast<const bf16x8*>(&sKV[rt * 16 + c][k0]);
                sc[rt] = MFMA16(ay, xb[kk], sc[rt]);
            }
        }
        #pragma unroll
        for (int rt = 0; rt < 8; ++rt) {
            const float4 wt4 = *reinterpret_cast<const float4*>(&sWt[rt * 16 + g * 4]);
            sc[rt][0] += wt4.x; sc[rt][1] += wt4.y;
            sc[rt][2] += wt4.z; sc[rt][3] += wt4.w;
        }
        float m = -3.0e38f;
        #pragma unroll
        for (int rt = 0; rt < 8; ++rt)
            #pragma unroll
            for (int r = 0; r < 4; ++r) m = fmaxf(m, sc[rt][r]);
        m = fmaxf(m, __shfl_xor(m, 16));
        m = fmaxf(m, __shfl_xor(m, 32));
        float ls = 0.f, wsum = 0.f;
        #pragma unroll
        for (int rt = 0; rt < 8; ++rt) {
            const float4 tm4 = *reinterpret_cast<const float4*>(&sTm[rt * 16 + g * 4]);
            const float tmr[4] = {tm4.x, tm4.y, tm4.z, tm4.w};
            #pragma unroll
            for (int r = 0; r < 4; ++r) {
                float p = __expf((sc[rt][r] - m) * rs);
                sc[rt][r] = p;
                ls += p;
                wsum += p * tmr[r];
            }
        }
        ls   += __shfl_xor(ls, 16);   ls   += __shfl_xor(ls, 32);
        wsum += __shfl_xor(wsum, 16); wsum += __shfl_xor(wsum, 32);
        l0 = ls;
        if (g == 0)
            out[(size_t)67108864 + (size_t)bn * 128 + s0 + c] = 1.0f - wsum / ls;
        #pragma unroll
        for (int rt = 0; rt < 8; ++rt) {
            bf16x4 pk;
            #pragma unroll
            for (int r = 0; r < 4; ++r) pk[r] = (bf16)sc[rt][r];
            *reinterpret_cast<bf16x4*>(&sX[s0 + c][rt * 16 + g * 4]) = pk;
        }
    }
    __syncthreads();                      // #4: all waves done reading sKV(Y)

    // ---------- V2 (regs) -> sKV as V2^T[h2][t] ----------
    {
        #pragma unroll
        for (int ct = 0; ct < 8; ++ct)
            *reinterpret_cast<bf16x4*>(&sKV[ct * 16 + c][s0 + g * 4]) = vpk[ct];
    }
    __syncthreads();                      // #5: V2^T published

    // ---------- out^T[h2][s] = V2^T·P / l + bias2 ; store f32 ----------
    {
        bf16x8 xp[4];
        #pragma unroll
        for (int kk = 0; kk < 4; ++kk)
            xp[kk] = *reinterpret_cast<const bf16x8*>(&sX[s0 + c][kk * 32 + g * 8]);
        f32x4 rc[8];
        #pragma unroll
        for (int rt = 0; rt < 8; ++rt) rc[rt] = FZ;
        #pragma unroll
        for (int kk = 0; kk < 4; ++kk) {
            const int k0 = kk * 32 + g * 8;
            #pragma unroll
            for (int rt = 0; rt < 8; ++rt) {
                bf16x8 avf = *reinterpret_cast<const bf16x8*>(&sKV[rt * 16 + c][k0]);
                rc[rt] = MFMA16(avf, xp[kk], rc[rt]);
            }
        }
        const float inv0 = __builtin_amdgcn_rcpf(l0);
        float* outb = out + (size_t)bn * 16384 + (size_t)(s0 + c) * 128;
        #pragma unroll
        for (int rt = 0; rt < 8; ++rt) {
            const int hb = rt * 16 + g * 4;
            const float4 b2 = *reinterpret_cast<const float4*>(bias2 + hb);
            float4 v;
            v.x = rc[rt][0] * inv0 + b2.x;
            v.y = rc[rt][1] * inv0 + b2.y;
            v.z = rc[rt][2] * inv0 + b2.z;
            v.w = rc[rt][3] * inv0 + b2.w;
            *reinterpret_cast<float4*>(outb + hb) = v;
        }
    }
}

extern "C" void kernel_launch(void* const* d_in, const int* in_sizes, int n_in,
                              void* d_out, int out_size, void* d_ws, size_t ws_size,
                              hipStream_t stream)
{
    (void)in_sizes; (void)n_in; (void)out_size; (void)ws_size;
    const float* xf     = (const float*)d_in[0];
    const float* ex     = (const float*)d_in[1];
    const int*   nf     = (const int*)d_in[2];
    const unsigned char* mask = (const unsigned char*)d_in[3];
    const float* W_in   = (const float*)d_in[4];
    const float* b_in   = (const float*)d_in[5];
    const float* W_t    = (const float*)d_in[6];
    const float* b_t    = (const float*)d_in[7];
    const float* E_node = (const float*)d_in[8];
    const float* W_q    = (const float*)d_in[9];
    const float* b_q    = (const float*)d_in[10];
    const float* W_k    = (const float*)d_in[11];
    const float* b_k    = (const float*)d_in[12];
    const float* W_v    = (const float*)d_in[13];
    const float* b_v    = (const float*)d_in[14];
    const float* W_o    = (const float*)d_in[15];
    const float* b_o    = (const float*)d_in[16];
    (void)b_k;
    float* out = (float*)d_out;

    // ws layout (bytes):
    //   [0, 32768)          W1T bf16 [h][k]
    //   [32768, 65536)      mstore bf16 G[a][b]
    //   [65536, 98304)      nstore bf16 N^T[h2][h]
    //   [98304, 1146880)    biasT f32 [16][128][128] (h fastest)
    //   [1146880, 1277952)  npart f32 [256][128]
    //   [1277952, 1278464)  vvec f32 [128]
    //   [1278464, 1278976)  bias2 f32 [128]
    bf16*  wsW    = (bf16*)d_ws;
    bf16*  mstore = wsW + 16384;
    bf16*  nstore = wsW + 32768;
    float* biasT  = (float*)((char*)d_ws + 98304);
    float* npart  = (float*)((char*)d_ws + 1146880);
    float* vvec   = (float*)((char*)d_ws + 1277952);
    float* bias2  = (float*)((char*)d_ws + 1278464);

    prep_weights<<<64, 256, 0, stream>>>(W_in, wsW);
    prep_G<<<128, 128, 0, stream>>>(W_q, W_k, b_q, mstore, vvec);
    prep_N<<<128, 128, 0, stream>>>(W_v, W_o, b_v, b_o, nstore, bias2);
    prep_npart<<<256, 128, 0, stream>>>(nf, E_node, W_in, npart);
    prep_bias<<<2048, 128, 0, stream>>>(ex, W_t, b_t, W_in, b_in, biasT);
    fused_main<<<4096, 512, 0, stream>>>(xf, mask, wsW, biasT, npart,
                                         vvec, bias2, out);
}